// Round 18
// baseline (430.642 us; speedup 1.0000x reference)
//
#include <hip/hip_runtime.h>
#include <hip/hip_bf16.h>

#define Bb 32
#define Nn 512
#define Cc 768
#define Hh 12
#define HDd 64
#define BND 358
// Q is pre-scaled by SCALE*log2(e) in the QKV epilogue -> logits in log2 domain
#define QS 0.18033688f

typedef unsigned short u16;
typedef unsigned int u32;
typedef __attribute__((ext_vector_type(8))) short bf16x8;
typedef __attribute__((ext_vector_type(4))) float f32x4;
typedef __attribute__((ext_vector_type(16))) float f32x16;
typedef __attribute__((ext_vector_type(4))) int i32x4;

__device__ __forceinline__ f32x4 MFMA16(bf16x8 a, bf16x8 b, f32x4 c) {
  return __builtin_amdgcn_mfma_f32_16x16x32_bf16(a, b, c, 0, 0, 0);
}
__device__ __forceinline__ f32x16 MFMA32(bf16x8 a, bf16x8 b, f32x16 c) {
  return __builtin_amdgcn_mfma_f32_32x32x16_bf16(a, b, c, 0, 0, 0);
}

__device__ __forceinline__ float fexp2(float x) { return __builtin_amdgcn_exp2f(x); }  // raw v_exp_f32

__device__ __forceinline__ u32 f2bf(float f) {
  u32 u = __builtin_bit_cast(u32, f);
  return (u + 0x7fffu + ((u >> 16) & 1u)) >> 16;
}
__device__ __forceinline__ u32 packbf2(float a, float b) { return f2bf(a) | (f2bf(b) << 16); }
__device__ __forceinline__ u32 cvtpk2(float a, float b) {
  float2 f2 = {a, b};
  __hip_bfloat162 h = __float22bfloat162_rn(f2);   // v_cvt_pk_bf16_f32
  u32 r;
  __builtin_memcpy(&r, &h, 4);
  return r;
}
__device__ __forceinline__ float bf2f(u16 h) { return __builtin_bit_cast(float, (u32)h << 16); }

__device__ __forceinline__ void async_copy16(void* lds, const void* g) {
  __builtin_amdgcn_global_load_lds((const __attribute__((address_space(1))) void*)g,
                                   (__attribute__((address_space(3))) void*)lds, 16, 0, 0);
}

// ---------------- elementwise conversions ----------------

__global__ __launch_bounds__(256) void k_convx(const float* __restrict__ x, u16* __restrict__ xb) {
  int gid = blockIdx.x * 256 + threadIdx.x;
  if (gid >= (Bb * Nn * Cc) / 4) return;
  float4 v = *(const float4*)&x[gid * 4];
  u32 p0 = packbf2(v.x, v.y), p1 = packbf2(v.z, v.w);
  uint2 st = {p0, p1};
  *(uint2*)&xb[gid * 4] = st;
}

// fused weight transposes: blocks [0,72) -> wqkv (768x2304), [72,96) -> wproj (768x768)
__global__ __launch_bounds__(256) void k_transw(const float* __restrict__ wqkv, u16* __restrict__ wqt,
                                                const float* __restrict__ wproj, u16* __restrict__ wpt) {
  __shared__ float tbuf[32][33];
  int bx = blockIdx.x;
  const float* src;
  u16* dst;
  int Ccols, cx;
  if (bx < 72) { src = wqkv; dst = wqt; Ccols = 2304; cx = bx; }
  else         { src = wproj; dst = wpt; Ccols = 768; cx = bx - 72; }
  int c0 = cx * 32, r0 = blockIdx.y * 32;
  int lx = threadIdx.x & 31, ly = threadIdx.x >> 5;  // 32 x 8
  #pragma unroll
  for (int rr = ly; rr < 32; rr += 8) tbuf[rr][lx] = src[(long)(r0 + rr) * Ccols + c0 + lx];
  __syncthreads();
  #pragma unroll
  for (int cc = ly; cc < 32; cc += 8) dst[(long)(c0 + cc) * 768 + r0 + lx] = (u16)f2bf(tbuf[lx][cc]);
}

// fused prep: lens (key-mask row sums), len-interleaved batch order, SCO zeroing.
// Single block, 256 threads.
__global__ __launch_bounds__(256) void k_prep(const int* __restrict__ mask, int* __restrict__ lens,
                                              int* __restrict__ ord, float* __restrict__ sco) {
  __shared__ int part[256];
  __shared__ int ls[32];
  int t = threadIdx.x;
  int b = t >> 3, p = t & 7;                        // 8 threads per batch
  const int* mrow = mask + (long)b * Nn * Nn;
  int s = 0;
  #pragma unroll
  for (int i = 0; i < 64; ++i) s += mrow[i * 8 + p];  // coalesced across threads
  part[t] = s;
  __syncthreads();
  if (p == 0) {
    int tot = 0;
    #pragma unroll
    for (int j = 0; j < 8; ++j) tot += part[t + j];
    ls[b] = tot;
    lens[b] = tot;
  }
  __syncthreads();
  if (t < 32) {
    int mylen = ls[t];
    int rank = 0;
    #pragma unroll
    for (int j = 0; j < 32; ++j) {
      int lj = ls[j];
      rank += (lj > mylen || (lj == mylen && j < t)) ? 1 : 0;
    }
    int s2 = (rank < 16) ? (2 * rank) : (2 * (31 - rank) + 1);
    ord[s2] = t;
  }
  for (int i = t; i < Bb * 511; i += 256) sco[i] = 0.f;
}

// ---------------- GEMM (R15 champion): 128x128 tile, BK=64, dbuf, 256 threads ----------------
// MODE 0, SWAP 1: Q/K blocks; quad spans n -> uint2 store into Q/K; Q pre-scaled.
// MODE 0, SWAP 0: V blocks; quad spans m -> uint2 store into TILED V.
// MODE 1, SWAP 1: proj; quad spans n -> float4 store + float4 bias.
template <int MODE, int SWAP>
__global__ __launch_bounds__(256) void k_gemm2(const u16* __restrict__ A, const u16* __restrict__ Bt,
                                               int nb0, u16* __restrict__ Qo, u16* __restrict__ Ko,
                                               u16* __restrict__ Vto, float* __restrict__ Co,
                                               const float* __restrict__ bias) {
  __shared__ u16 As[2][128 * 64];
  __shared__ u16 Bs[2][128 * 64];
  int m0 = blockIdx.x * 128;
  int nb = nb0 + blockIdx.y * 128;
  int t = threadIdx.x, lane = t & 63, wave = t >> 6;
  int wr = wave >> 1, wc = wave & 1;
  int qlane = lane & 15, g = lane >> 4;
  f32x4 acc[4][4] = {};

  auto stage = [&](int kt, int buf) {
    #pragma unroll
    for (int i = 0; i < 4; ++i) {
      int chunk = i * 256 + t;
      int row = chunk >> 3;
      int cp = (chunk & 7) << 4;
      int src = cp ^ ((row & 7) << 4);    // inverse-swizzled source byte-pos
      const u16* ga = A + (long)(m0 + row) * 768 + kt * 64 + (src >> 1);
      const u16* gb = Bt + (long)(nb + row) * 768 + kt * 64 + (src >> 1);
      async_copy16(&As[buf][(i * 256 + wave * 64) * 8], ga);
      async_copy16(&Bs[buf][(i * 256 + wave * 64) * 8], gb);
    }
  };

  auto compute = [&](int buf) {
    #pragma unroll
    for (int kk = 0; kk < 2; ++kk) {
      bf16x8 af[4], bf[4];
      #pragma unroll
      for (int x = 0; x < 4; ++x) {
        int ra = wr * 64 + x * 16 + qlane;
        int ca = (kk * 64 + g * 16) ^ ((ra & 7) << 4);   // swizzled read byte-pos
        af[x] = *(const bf16x8*)&As[buf][ra * 64 + (ca >> 1)];
        int rb = wc * 64 + x * 16 + qlane;
        int cb = (kk * 64 + g * 16) ^ ((rb & 7) << 4);
        bf[x] = *(const bf16x8*)&Bs[buf][rb * 64 + (cb >> 1)];
      }
      #pragma unroll
      for (int mi = 0; mi < 4; ++mi)
        #pragma unroll
        for (int ni = 0; ni < 4; ++ni)
          acc[mi][ni] = SWAP ? MFMA16(bf[ni], af[mi], acc[mi][ni])
                             : MFMA16(af[mi], bf[ni], acc[mi][ni]);
    }
  };

  stage(0, 0);
  __syncthreads();
  int cur = 0;
  for (int kt = 0; kt < 12; ++kt) {
    if (kt < 11) stage(kt + 1, cur ^ 1);  // prefetch flies during compute
    compute(cur);
    __syncthreads();
    cur ^= 1;
  }

  if (MODE == 0 && SWAP == 1) {
    #pragma unroll
    for (int mi = 0; mi < 4; ++mi) {
      int m = m0 + wr * 64 + mi * 16 + qlane;
      int b = m >> 9, qi = m & 511;
      #pragma unroll
      for (int ni = 0; ni < 4; ++ni) {
        int nf = nb + wc * 64 + ni * 16 + g * 4;
        int which = nf >= 768;
        int rem = nf - which * 768;
        int hh = rem >> 6, d0 = rem & 63;
        u16* dst = (which ? Ko : Qo) + ((long)(b * Hh + hh) * Nn + qi) * HDd + d0;
        float sc = which ? 1.f : QS;   // pre-scale Q into log2 softmax domain
        uint2 st = {packbf2(acc[mi][ni][0] * sc, acc[mi][ni][1] * sc),
                    packbf2(acc[mi][ni][2] * sc, acc[mi][ni][3] * sc)};
        *(uint2*)dst = st;
      }
    }
  } else if (MODE == 0) {
    // V tiled: subtile = qi>>5 (4KB of 64d x 32k), within: d*32 + (qi&31)
    #pragma unroll
    for (int mi = 0; mi < 4; ++mi) {
      int m = m0 + wr * 64 + mi * 16 + g * 4;
      int b = m >> 9, qi = m & 511;
      #pragma unroll
      for (int ni = 0; ni < 4; ++ni) {
        int rem = nb + wc * 64 + ni * 16 + qlane - 1536;
        int hh = rem >> 6, d = rem & 63;
        u16* dst = Vto + (long)(b * Hh + hh) * (Nn * HDd) + (qi >> 5) * 2048 + d * 32 + (qi & 31);
        uint2 st = {packbf2(acc[mi][ni][0], acc[mi][ni][1]),
                    packbf2(acc[mi][ni][2], acc[mi][ni][3])};
        *(uint2*)dst = st;
      }
    }
  } else {
    // proj (SWAP=1): quad spans n -> float4 store + float4 bias
    #pragma unroll
    for (int mi = 0; mi < 4; ++mi) {
      int m = m0 + wr * 64 + mi * 16 + qlane;
      #pragma unroll
      for (int ni = 0; ni < 4; ++ni) {
        int n0 = nb + wc * 64 + ni * 16 + g * 4;
        float4 bv = *(const float4*)&bias[n0];
        float4 st = {acc[mi][ni][0] + bv.x, acc[mi][ni][1] + bv.y,
                     acc[mi][ni][2] + bv.z, acc[mi][ni][3] + bv.w};
        *(float4*)&Co[(long)m * Cc + n0] = st;
      }
    }
  }
}

// ---------------- fused attention v8 (R12 champion) + VGPR cap for 4 waves/SIMD ----------------
// 3072 one-wave blocks. bid = chunk*384 + bh: all 8 q-chunks of one (b,h) share
// bid%8 -> same XCD L2; one batch's heads stream per XCD round (L2-friendly).
// b = ord[bh/12] (len-interleaved) balances per-CU work. 2-deep register
// prefetch (named buffers). exp2 = single v_exp_f32.
// __launch_bounds__(64,4): cap VGPR at 128 -> 4 waves/SIMD (was 136 -> 3).
__global__ __launch_bounds__(64, 4) void k_attn(const u16* __restrict__ Q, const u16* __restrict__ K,
                                                const u16* __restrict__ Vt, const int* __restrict__ lens,
                                                const int* __restrict__ ord, u16* __restrict__ AO) {
  int lane = threadIdx.x;
  int bid = blockIdx.x;
  int bh = bid % (Bb * Hh);
  int chunk = bid / (Bb * Hh);
  int b = ord[bh / Hh];
  int h = bh % Hh;
  int q0w = chunk * 64;
  int ln = lane & 31, hi = lane >> 5;
  int len = lens[b];
  int nt = (len + 31) >> 5;

  const u16* Qb = Q + (long)(b * Hh + h) * Nn * HDd;
  const u16* Kb = K + (long)(b * Hh + h) * Nn * HDd;
  const u16* Vb = Vt + (long)(b * Hh + h) * Nn * HDd;  // tiled: 16 x (64d x 32k)

  // Q fragments: B-operand of mfma32 (Q^T): lane holds Q[q0+ln][ds*16+hi*8+j]
  bf16x8 qf[2][4];
  #pragma unroll
  for (int qt = 0; qt < 2; ++qt)
    #pragma unroll
    for (int ds = 0; ds < 4; ++ds)
      qf[qt][ds] = *(const bf16x8*)(Qb + (q0w + qt * 32 + ln) * HDd + ds * 16 + hi * 8);

  f32x16 o[2][2] = {};  // [qt][dt] : o^T[d][q], lane q=ln, 16 d-vals
  float l[2] = {0.f, 0.f};

  auto loadt = [&](bf16x8 (&kf)[4], bf16x8 (&vf)[2][2], int t) {
    int k0 = t * 32;
    #pragma unroll
    for (int ds = 0; ds < 4; ++ds)
      kf[ds] = *(const bf16x8*)(Kb + (k0 + ln) * HDd + ds * 16 + hi * 8);
    #pragma unroll
    for (int dt = 0; dt < 2; ++dt)
      #pragma unroll
      for (int ks = 0; ks < 2; ++ks)
        vf[dt][ks] = *(const bf16x8*)(Vb + t * 2048 + (dt * 32 + ln) * 32 + ks * 16 + hi * 8);
  };

  auto compute = [&](const bf16x8 (&kf)[4], const bf16x8 (&vf)[2][2], int t) {
    int k0 = t * 32;
    bool bdry = (k0 + 32 > len);
    int khi = k0 + 4 * hi;
    #pragma unroll
    for (int qt = 0; qt < 2; ++qt) {
      f32x16 st = {};
      #pragma unroll
      for (int ds = 0; ds < 4; ++ds) st = MFMA32(kf[ds], qf[qt][ds], st);
      // C-layout: row(key within 32) = (r&3)+8*(r>>2)+4*hi, col(q)=ln
      if (bdry) {
        #pragma unroll
        for (int r = 0; r < 16; ++r) {
          int key = khi + (r & 3) + 8 * (r >> 2);
          if (key >= len) st[r] = -1e9f;
        }
      }
      float p[16];
      #pragma unroll
      for (int r = 0; r < 16; ++r) p[r] = fexp2(st[r]);
      l[qt] += (((p[0] + p[1]) + (p[2] + p[3])) + ((p[4] + p[5]) + (p[6] + p[7]))) +
               (((p[8] + p[9]) + (p[10] + p[11])) + ((p[12] + p[13]) + (p[14] + p[15])));
      u32 wA0 = cvtpk2(p[0], p[1]), wA1 = cvtpk2(p[2], p[3]);
      u32 wA2 = cvtpk2(p[4], p[5]), wA3 = cvtpk2(p[6], p[7]);
      asm volatile("v_permlane32_swap_b32 %0, %1" : "+v"(wA0), "+v"(wA2));
      asm volatile("v_permlane32_swap_b32 %0, %1" : "+v"(wA1), "+v"(wA3));
      u32 wB0 = cvtpk2(p[8], p[9]), wB1 = cvtpk2(p[10], p[11]);
      u32 wB2 = cvtpk2(p[12], p[13]), wB3 = cvtpk2(p[14], p[15]);
      asm volatile("v_permlane32_swap_b32 %0, %1" : "+v"(wB0), "+v"(wB2));
      asm volatile("v_permlane32_swap_b32 %0, %1" : "+v"(wB1), "+v"(wB3));
      i32x4 bi0 = {(int)wA0, (int)wA1, (int)wA2, (int)wA3};
      i32x4 bi1 = {(int)wB0, (int)wB1, (int)wB2, (int)wB3};
      bf16x8 pb0 = __builtin_bit_cast(bf16x8, bi0);
      bf16x8 pb1 = __builtin_bit_cast(bf16x8, bi1);
      #pragma unroll
      for (int dt = 0; dt < 2; ++dt) {
        o[qt][dt] = MFMA32(vf[dt][0], pb0, o[qt][dt]);
        o[qt][dt] = MFMA32(vf[dt][1], pb1, o[qt][dt]);
      }
    }
  };

  // 2-deep software pipeline: named buffers (no runtime-indexed arrays)
  bf16x8 kfA[4], vfA[2][2], kfB[4], vfB[2][2];
  loadt(kfA, vfA, 0);
  int t = 0;
  #pragma unroll 1
  for (; t + 2 <= nt; t += 2) {
    loadt(kfB, vfB, t + 1);
    compute(kfA, vfA, t);
    if (t + 2 < nt) loadt(kfA, vfA, t + 2);
    compute(kfB, vfB, t + 1);
  }
  if (t < nt) compute(kfA, vfA, t);

  #pragma unroll
  for (int qt = 0; qt < 2; ++qt) {
    float ls = l[qt] + __shfl_xor(l[qt], 32);
    float inv = 1.f / ls;
    u16* outp = AO + ((long)(b * Nn + q0w + qt * 32 + ln) * Cc) + h * HDd;
    #pragma unroll
    for (int dt = 0; dt < 2; ++dt) {
      #pragma unroll
      for (int qd = 0; qd < 4; ++qd) {  // reg quad -> d = dt*32 + 8*qd + 4*hi + 0..3
        uint2 st2 = {cvtpk2(o[qt][dt][4 * qd + 0] * inv, o[qt][dt][4 * qd + 1] * inv),
                     cvtpk2(o[qt][dt][4 * qd + 2] * inv, o[qt][dt][4 * qd + 3] * inv)};
        *(uint2*)(outp + dt * 32 + 8 * qd + 4 * hi) = st2;
      }
    }
  }
}

// ---------------- CLS-row scores (one block per (b,h), atomic accumulate) ----------------
__global__ __launch_bounds__(256) void k_cls(const u16* __restrict__ Q, const u16* __restrict__ K,
                                             const int* __restrict__ lens, float* __restrict__ scores) {
  int bh = blockIdx.x;  // 0..383
  int b = bh / Hh;
  int t = threadIdx.x;
  int len = lens[b];
  __shared__ float qrow[64];
  __shared__ float red[256];
  const u16* Qb = Q + (long)bh * Nn * HDd;
  const u16* Kb = K + (long)bh * Nn * HDd;
  if (t < 64) qrow[t] = bf2f(Qb[t]);   // CLS query, pre-scaled (log2 domain)
  __syncthreads();
  const bf16x8* kr0 = (const bf16x8*)(Kb + t * HDd);
  const bf16x8* kr1 = (const bf16x8*)(Kb + (t + 256) * HDd);
  float d0 = 0.f, d1 = 0.f;
  #pragma unroll
  for (int c8 = 0; c8 < 8; ++c8) {
    bf16x8 kv0 = kr0[c8], kv1 = kr1[c8];
    #pragma unroll
    for (int j = 0; j < 8; ++j) {
      float qv = qrow[c8 * 8 + j];
      d0 += qv * bf2f((u16)kv0[j]);
      d1 += qv * bf2f((u16)kv1[j]);
    }
  }
  float l0 = (t < len) ? d0 : -1e9f;
  float l1 = (t + 256 < len) ? d1 : -1e9f;
  red[t] = fmaxf(l0, l1);
  __syncthreads();
  for (int ss = 128; ss > 0; ss >>= 1) {
    if (t < ss) red[t] = fmaxf(red[t], red[t + ss]);
    __syncthreads();
  }
  float mx = red[0];
  __syncthreads();
  float e0 = fexp2(l0 - mx), e1 = fexp2(l1 - mx);
  red[t] = e0 + e1;
  __syncthreads();
  for (int ss = 128; ss > 0; ss >>= 1) {
    if (t < ss) red[t] += red[t + ss];
    __syncthreads();
  }
  float w = (1.f / 12.f) / red[0];
  if (t >= 1) atomicAdd(&scores[b * 511 + (t - 1)], e0 * w);
  atomicAdd(&scores[b * 511 + (t + 255)], e1 * w);
}

// ---------------- top-k (bitonic sort 512, desc score / asc idx) ----------------
__device__ __forceinline__ bool sless(float sa, int ia, float sb, int ib) {
  return (sa > sb) || (sa == sb && ia < ib);
}

__global__ __launch_bounds__(256) void k_topk(const float* __restrict__ scores,
                                              const int* __restrict__ lens, float* __restrict__ dout) {
  int b = blockIdx.x, t = threadIdx.x;
  __shared__ float sc[512];
  __shared__ int id[512];
  float ninf = -__builtin_inff();
  int len = lens[b];
  for (int i = t; i < 512; i += 256) {
    sc[i] = (i < 511 && (i + 1) < len) ? scores[b * 511 + i] : ninf;
    id[i] = i;
  }
  for (int k = 2; k <= 512; k <<= 1) {
    for (int j = k >> 1; j > 0; j >>= 1) {
      __syncthreads();
      for (int i = t; i < 512; i += 256) {
        int ixj = i ^ j;
        if (ixj > i) {
          float si = sc[i], sj = sc[ixj];
          int ii = id[i], ij = id[ixj];
          bool up = ((i & k) == 0);
          bool dosw = up ? sless(sj, ij, si, ii) : sless(si, ii, sj, ij);
          if (dosw) {
            sc[i] = sj; sc[ixj] = si;
            id[i] = ij; id[ixj] = ii;
          }
        }
      }
    }
  }
  __syncthreads();
  int left = (int)ceilf((float)(len - 1) * 0.7f);
  const long OFF_IDX = (long)Bb * Nn * Cc + (long)Bb * BND * Cc;
  for (int p = t; p < BND; p += 256) {
    dout[OFF_IDX + (long)b * BND + p] = (p < left) ? (float)id[p] : 1e9f;
  }
  if (b == 0 && t == 0) dout[OFF_IDX + (long)Bb * BND] = (float)BND;
}

__global__ __launch_bounds__(256) void k_bcast(float* __restrict__ dout) {
  long gid = (long)blockIdx.x * 256 + threadIdx.x;
  const long total = (long)Bb * BND * (Cc / 4);
  if (gid >= total) return;
  long bp = gid / (Cc / 4);
  int c4 = (int)(gid % (Cc / 4));
  const long OFF_INDEX = (long)Bb * Nn * Cc;
  const long OFF_IDX = OFF_INDEX + (long)Bb * BND * Cc;
  float v = dout[OFF_IDX + bp];
  float4 f = {v, v, v, v};
  *(float4*)&dout[OFF_INDEX + bp * Cc + (long)c4 * 4] = f;
}

// ---------------- launch ----------------
extern "C" void kernel_launch(void* const* d_in, const int* in_sizes, int n_in,
                              void* d_out, int out_size, void* d_ws, size_t ws_size,
                              hipStream_t stream) {
  const float* x = (const float*)d_in[0];
  const int* mask = (const int*)d_in[1];
  const float* wqkv = (const float*)d_in[2];
  const float* wproj = (const float*)d_in[3];
  const float* bproj = (const float*)d_in[4];
  float* out = (float*)d_out;

  char* ws = (char*)d_ws;
  u16* Qw  = (u16*)(ws);                    // 25165824 B
  u16* Kw  = (u16*)(ws + 25165824L);        // 25165824 B
  u16* Vtw = (u16*)(ws + 50331648L);        // 25165824 B (tiled layout)
  u16* XB  = (u16*)(ws + 75497472L);        // 25165824 B (x bf16; reused as attn out)
  u16* AO  = XB;
  u16* WQT = (u16*)(ws + 100663296L);       // 3538944 B
  u16* WPT = (u16*)(ws + 104202240L);       // 1179648 B
  float* SCO = (float*)(ws + 105381888L);   // 65536 B
  int* LEN = (int*)(ws + 105447424L);       // 128 B
  int* ORD = (int*)(ws + 105447552L);       // 128 B

  k_convx<<<12288, 256, 0, stream>>>(x, XB);
  k_transw<<<dim3(96, 24), 256, 0, stream>>>(wqkv, WQT, wproj, WPT);
  k_prep<<<1, 256, 0, stream>>>(mask, LEN, ORD, SCO);
  k_gemm2<0, 1><<<dim3(128, 12), 256, 0, stream>>>(XB, WQT, 0, Qw, Kw, nullptr, nullptr, nullptr);
  k_gemm2<0, 0><<<dim3(128, 6), 256, 0, stream>>>(XB, WQT, 1536, nullptr, nullptr, Vtw, nullptr, nullptr);
  k_attn<<<3072, 64, 0, stream>>>(Qw, Kw, Vtw, LEN, ORD, AO);
  k_gemm2<1, 1><<<dim3(128, 6), 256, 0, stream>>>(AO, WPT, 0, nullptr, nullptr, nullptr, out, bproj);
  k_cls<<<384, 256, 0, stream>>>(Qw, Kw, LEN, SCO);
  k_topk<<<32, 256, 0, stream>>>(SCO, LEN, out);
  k_bcast<<<8592, 256, 0, stream>>>(out);
}

// Round 19
// 219.814 us; speedup vs baseline: 1.9591x; 1.9591x over previous
//
#include <hip/hip_runtime.h>
#include <hip/hip_bf16.h>

#define Bb 32
#define Nn 512
#define Cc 768
#define Hh 12
#define HDd 64
#define BND 358
// Q is pre-scaled by SCALE*log2(e) in the QKV epilogue -> logits in log2 domain
#define QS 0.18033688f

typedef unsigned short u16;
typedef unsigned int u32;
typedef __attribute__((ext_vector_type(8))) short bf16x8;
typedef __attribute__((ext_vector_type(4))) float f32x4;
typedef __attribute__((ext_vector_type(16))) float f32x16;
typedef __attribute__((ext_vector_type(4))) int i32x4;

__device__ __forceinline__ f32x4 MFMA16(bf16x8 a, bf16x8 b, f32x4 c) {
  return __builtin_amdgcn_mfma_f32_16x16x32_bf16(a, b, c, 0, 0, 0);
}
__device__ __forceinline__ f32x16 MFMA32(bf16x8 a, bf16x8 b, f32x16 c) {
  return __builtin_amdgcn_mfma_f32_32x32x16_bf16(a, b, c, 0, 0, 0);
}

__device__ __forceinline__ float fexp2(float x) { return __builtin_amdgcn_exp2f(x); }  // raw v_exp_f32

__device__ __forceinline__ u32 f2bf(float f) {
  u32 u = __builtin_bit_cast(u32, f);
  return (u + 0x7fffu + ((u >> 16) & 1u)) >> 16;
}
__device__ __forceinline__ u32 packbf2(float a, float b) { return f2bf(a) | (f2bf(b) << 16); }
__device__ __forceinline__ u32 cvtpk2(float a, float b) {
  float2 f2 = {a, b};
  __hip_bfloat162 h = __float22bfloat162_rn(f2);   // v_cvt_pk_bf16_f32
  u32 r;
  __builtin_memcpy(&r, &h, 4);
  return r;
}
__device__ __forceinline__ float bf2f(u16 h) { return __builtin_bit_cast(float, (u32)h << 16); }

__device__ __forceinline__ void async_copy16(void* lds, const void* g) {
  __builtin_amdgcn_global_load_lds((const __attribute__((address_space(1))) void*)g,
                                   (__attribute__((address_space(3))) void*)lds, 16, 0, 0);
}

// ---------------- elementwise conversions ----------------

__global__ __launch_bounds__(256) void k_convx(const float* __restrict__ x, u16* __restrict__ xb) {
  int gid = blockIdx.x * 256 + threadIdx.x;
  if (gid >= (Bb * Nn * Cc) / 4) return;
  float4 v = *(const float4*)&x[gid * 4];
  u32 p0 = packbf2(v.x, v.y), p1 = packbf2(v.z, v.w);
  uint2 st = {p0, p1};
  *(uint2*)&xb[gid * 4] = st;
}

// fused weight transposes: blocks [0,72) -> wqkv (768x2304), [72,96) -> wproj (768x768)
__global__ __launch_bounds__(256) void k_transw(const float* __restrict__ wqkv, u16* __restrict__ wqt,
                                                const float* __restrict__ wproj, u16* __restrict__ wpt) {
  __shared__ float tbuf[32][33];
  int bx = blockIdx.x;
  const float* src;
  u16* dst;
  int Ccols, cx;
  if (bx < 72) { src = wqkv; dst = wqt; Ccols = 2304; cx = bx; }
  else         { src = wproj; dst = wpt; Ccols = 768; cx = bx - 72; }
  int c0 = cx * 32, r0 = blockIdx.y * 32;
  int lx = threadIdx.x & 31, ly = threadIdx.x >> 5;  // 32 x 8
  #pragma unroll
  for (int rr = ly; rr < 32; rr += 8) tbuf[rr][lx] = src[(long)(r0 + rr) * Ccols + c0 + lx];
  __syncthreads();
  #pragma unroll
  for (int cc = ly; cc < 32; cc += 8) dst[(long)(c0 + cc) * 768 + r0 + lx] = (u16)f2bf(tbuf[lx][cc]);
}

// fused prep: lens (key-mask row sums), len-interleaved batch order, SCO zeroing.
// Single block, 256 threads.
__global__ __launch_bounds__(256) void k_prep(const int* __restrict__ mask, int* __restrict__ lens,
                                              int* __restrict__ ord, float* __restrict__ sco) {
  __shared__ int part[256];
  __shared__ int ls[32];
  int t = threadIdx.x;
  int b = t >> 3, p = t & 7;                        // 8 threads per batch
  const int* mrow = mask + (long)b * Nn * Nn;
  int s = 0;
  #pragma unroll
  for (int i = 0; i < 64; ++i) s += mrow[i * 8 + p];  // coalesced across threads
  part[t] = s;
  __syncthreads();
  if (p == 0) {
    int tot = 0;
    #pragma unroll
    for (int j = 0; j < 8; ++j) tot += part[t + j];
    ls[b] = tot;
    lens[b] = tot;
  }
  __syncthreads();
  if (t < 32) {
    int mylen = ls[t];
    int rank = 0;
    #pragma unroll
    for (int j = 0; j < 32; ++j) {
      int lj = ls[j];
      rank += (lj > mylen || (lj == mylen && j < t)) ? 1 : 0;
    }
    int s2 = (rank < 16) ? (2 * rank) : (2 * (31 - rank) + 1);
    ord[s2] = t;
  }
  for (int i = t; i < Bb * 511; i += 256) sco[i] = 0.f;
}

// ---------------- GEMM (R15 champion): 128x128 tile, BK=64, dbuf, 256 threads ----------------
// MODE 0, SWAP 1: Q/K blocks; quad spans n -> uint2 store into Q/K; Q pre-scaled.
// MODE 0, SWAP 0: V blocks; quad spans m -> uint2 store into TILED V.
// MODE 1, SWAP 1: proj; quad spans n -> float4 store + float4 bias.
template <int MODE, int SWAP>
__global__ __launch_bounds__(256) void k_gemm2(const u16* __restrict__ A, const u16* __restrict__ Bt,
                                               int nb0, u16* __restrict__ Qo, u16* __restrict__ Ko,
                                               u16* __restrict__ Vto, float* __restrict__ Co,
                                               const float* __restrict__ bias) {
  __shared__ u16 As[2][128 * 64];
  __shared__ u16 Bs[2][128 * 64];
  int m0 = blockIdx.x * 128;
  int nb = nb0 + blockIdx.y * 128;
  int t = threadIdx.x, lane = t & 63, wave = t >> 6;
  int wr = wave >> 1, wc = wave & 1;
  int qlane = lane & 15, g = lane >> 4;
  f32x4 acc[4][4] = {};

  auto stage = [&](int kt, int buf) {
    #pragma unroll
    for (int i = 0; i < 4; ++i) {
      int chunk = i * 256 + t;
      int row = chunk >> 3;
      int cp = (chunk & 7) << 4;
      int src = cp ^ ((row & 7) << 4);    // inverse-swizzled source byte-pos
      const u16* ga = A + (long)(m0 + row) * 768 + kt * 64 + (src >> 1);
      const u16* gb = Bt + (long)(nb + row) * 768 + kt * 64 + (src >> 1);
      async_copy16(&As[buf][(i * 256 + wave * 64) * 8], ga);
      async_copy16(&Bs[buf][(i * 256 + wave * 64) * 8], gb);
    }
  };

  auto compute = [&](int buf) {
    #pragma unroll
    for (int kk = 0; kk < 2; ++kk) {
      bf16x8 af[4], bf[4];
      #pragma unroll
      for (int x = 0; x < 4; ++x) {
        int ra = wr * 64 + x * 16 + qlane;
        int ca = (kk * 64 + g * 16) ^ ((ra & 7) << 4);   // swizzled read byte-pos
        af[x] = *(const bf16x8*)&As[buf][ra * 64 + (ca >> 1)];
        int rb = wc * 64 + x * 16 + qlane;
        int cb = (kk * 64 + g * 16) ^ ((rb & 7) << 4);
        bf[x] = *(const bf16x8*)&Bs[buf][rb * 64 + (cb >> 1)];
      }
      #pragma unroll
      for (int mi = 0; mi < 4; ++mi)
        #pragma unroll
        for (int ni = 0; ni < 4; ++ni)
          acc[mi][ni] = SWAP ? MFMA16(bf[ni], af[mi], acc[mi][ni])
                             : MFMA16(af[mi], bf[ni], acc[mi][ni]);
    }
  };

  stage(0, 0);
  __syncthreads();
  int cur = 0;
  for (int kt = 0; kt < 12; ++kt) {
    if (kt < 11) stage(kt + 1, cur ^ 1);  // prefetch flies during compute
    compute(cur);
    __syncthreads();
    cur ^= 1;
  }

  if (MODE == 0 && SWAP == 1) {
    #pragma unroll
    for (int mi = 0; mi < 4; ++mi) {
      int m = m0 + wr * 64 + mi * 16 + qlane;
      int b = m >> 9, qi = m & 511;
      #pragma unroll
      for (int ni = 0; ni < 4; ++ni) {
        int nf = nb + wc * 64 + ni * 16 + g * 4;
        int which = nf >= 768;
        int rem = nf - which * 768;
        int hh = rem >> 6, d0 = rem & 63;
        u16* dst = (which ? Ko : Qo) + ((long)(b * Hh + hh) * Nn + qi) * HDd + d0;
        float sc = which ? 1.f : QS;   // pre-scale Q into log2 softmax domain
        uint2 st = {packbf2(acc[mi][ni][0] * sc, acc[mi][ni][1] * sc),
                    packbf2(acc[mi][ni][2] * sc, acc[mi][ni][3] * sc)};
        *(uint2*)dst = st;
      }
    }
  } else if (MODE == 0) {
    // V tiled: subtile = qi>>5 (4KB of 64d x 32k), within: d*32 + (qi&31)
    #pragma unroll
    for (int mi = 0; mi < 4; ++mi) {
      int m = m0 + wr * 64 + mi * 16 + g * 4;
      int b = m >> 9, qi = m & 511;
      #pragma unroll
      for (int ni = 0; ni < 4; ++ni) {
        int rem = nb + wc * 64 + ni * 16 + qlane - 1536;
        int hh = rem >> 6, d = rem & 63;
        u16* dst = Vto + (long)(b * Hh + hh) * (Nn * HDd) + (qi >> 5) * 2048 + d * 32 + (qi & 31);
        uint2 st = {packbf2(acc[mi][ni][0], acc[mi][ni][1]),
                    packbf2(acc[mi][ni][2], acc[mi][ni][3])};
        *(uint2*)dst = st;
      }
    }
  } else {
    // proj (SWAP=1): quad spans n -> float4 store + float4 bias
    #pragma unroll
    for (int mi = 0; mi < 4; ++mi) {
      int m = m0 + wr * 64 + mi * 16 + qlane;
      #pragma unroll
      for (int ni = 0; ni < 4; ++ni) {
        int n0 = nb + wc * 64 + ni * 16 + g * 4;
        float4 bv = *(const float4*)&bias[n0];
        float4 st = {acc[mi][ni][0] + bv.x, acc[mi][ni][1] + bv.y,
                     acc[mi][ni][2] + bv.z, acc[mi][ni][3] + bv.w};
        *(float4*)&Co[(long)m * Cc + n0] = st;
      }
    }
  }
}

// ---------------- fused attention v8 (R12/R15 champion): R10 grid + raw v_exp_f32 ----------------
// 3072 one-wave blocks. bid = chunk*384 + bh: all 8 q-chunks of one (b,h) share
// bid%8 -> same XCD L2; one batch's heads stream per XCD round (L2-friendly).
// b = ord[bh/12] (len-interleaved) balances per-CU work. 2-deep register
// prefetch (named buffers). exp2 = single v_exp_f32.
// NO min-waves bound (R18 lesson: capping VGPR below natural usage -> scratch spill).
__global__ __launch_bounds__(64) void k_attn(const u16* __restrict__ Q, const u16* __restrict__ K,
                                             const u16* __restrict__ Vt, const int* __restrict__ lens,
                                             const int* __restrict__ ord, u16* __restrict__ AO) {
  int lane = threadIdx.x;
  int bid = blockIdx.x;
  int bh = bid % (Bb * Hh);
  int chunk = bid / (Bb * Hh);
  int b = ord[bh / Hh];
  int h = bh % Hh;
  int q0w = chunk * 64;
  int ln = lane & 31, hi = lane >> 5;
  int len = lens[b];
  int nt = (len + 31) >> 5;

  const u16* Qb = Q + (long)(b * Hh + h) * Nn * HDd;
  const u16* Kb = K + (long)(b * Hh + h) * Nn * HDd;
  const u16* Vb = Vt + (long)(b * Hh + h) * Nn * HDd;  // tiled: 16 x (64d x 32k)

  // Q fragments: B-operand of mfma32 (Q^T): lane holds Q[q0+ln][ds*16+hi*8+j]
  bf16x8 qf[2][4];
  #pragma unroll
  for (int qt = 0; qt < 2; ++qt)
    #pragma unroll
    for (int ds = 0; ds < 4; ++ds)
      qf[qt][ds] = *(const bf16x8*)(Qb + (q0w + qt * 32 + ln) * HDd + ds * 16 + hi * 8);

  f32x16 o[2][2] = {};  // [qt][dt] : o^T[d][q], lane q=ln, 16 d-vals
  float l[2] = {0.f, 0.f};

  auto loadt = [&](bf16x8 (&kf)[4], bf16x8 (&vf)[2][2], int t) {
    int k0 = t * 32;
    #pragma unroll
    for (int ds = 0; ds < 4; ++ds)
      kf[ds] = *(const bf16x8*)(Kb + (k0 + ln) * HDd + ds * 16 + hi * 8);
    #pragma unroll
    for (int dt = 0; dt < 2; ++dt)
      #pragma unroll
      for (int ks = 0; ks < 2; ++ks)
        vf[dt][ks] = *(const bf16x8*)(Vb + t * 2048 + (dt * 32 + ln) * 32 + ks * 16 + hi * 8);
  };

  auto compute = [&](const bf16x8 (&kf)[4], const bf16x8 (&vf)[2][2], int t) {
    int k0 = t * 32;
    bool bdry = (k0 + 32 > len);
    int khi = k0 + 4 * hi;
    #pragma unroll
    for (int qt = 0; qt < 2; ++qt) {
      f32x16 st = {};
      #pragma unroll
      for (int ds = 0; ds < 4; ++ds) st = MFMA32(kf[ds], qf[qt][ds], st);
      // C-layout: row(key within 32) = (r&3)+8*(r>>2)+4*hi, col(q)=ln
      if (bdry) {
        #pragma unroll
        for (int r = 0; r < 16; ++r) {
          int key = khi + (r & 3) + 8 * (r >> 2);
          if (key >= len) st[r] = -1e9f;
        }
      }
      float p[16];
      #pragma unroll
      for (int r = 0; r < 16; ++r) p[r] = fexp2(st[r]);
      l[qt] += (((p[0] + p[1]) + (p[2] + p[3])) + ((p[4] + p[5]) + (p[6] + p[7]))) +
               (((p[8] + p[9]) + (p[10] + p[11])) + ((p[12] + p[13]) + (p[14] + p[15])));
      u32 wA0 = cvtpk2(p[0], p[1]), wA1 = cvtpk2(p[2], p[3]);
      u32 wA2 = cvtpk2(p[4], p[5]), wA3 = cvtpk2(p[6], p[7]);
      asm volatile("v_permlane32_swap_b32 %0, %1" : "+v"(wA0), "+v"(wA2));
      asm volatile("v_permlane32_swap_b32 %0, %1" : "+v"(wA1), "+v"(wA3));
      u32 wB0 = cvtpk2(p[8], p[9]), wB1 = cvtpk2(p[10], p[11]);
      u32 wB2 = cvtpk2(p[12], p[13]), wB3 = cvtpk2(p[14], p[15]);
      asm volatile("v_permlane32_swap_b32 %0, %1" : "+v"(wB0), "+v"(wB2));
      asm volatile("v_permlane32_swap_b32 %0, %1" : "+v"(wB1), "+v"(wB3));
      i32x4 bi0 = {(int)wA0, (int)wA1, (int)wA2, (int)wA3};
      i32x4 bi1 = {(int)wB0, (int)wB1, (int)wB2, (int)wB3};
      bf16x8 pb0 = __builtin_bit_cast(bf16x8, bi0);
      bf16x8 pb1 = __builtin_bit_cast(bf16x8, bi1);
      #pragma unroll
      for (int dt = 0; dt < 2; ++dt) {
        o[qt][dt] = MFMA32(vf[dt][0], pb0, o[qt][dt]);
        o[qt][dt] = MFMA32(vf[dt][1], pb1, o[qt][dt]);
      }
    }
  };

  // 2-deep software pipeline: named buffers (no runtime-indexed arrays)
  bf16x8 kfA[4], vfA[2][2], kfB[4], vfB[2][2];
  loadt(kfA, vfA, 0);
  int t = 0;
  #pragma unroll 1
  for (; t + 2 <= nt; t += 2) {
    loadt(kfB, vfB, t + 1);
    compute(kfA, vfA, t);
    if (t + 2 < nt) loadt(kfA, vfA, t + 2);
    compute(kfB, vfB, t + 1);
  }
  if (t < nt) compute(kfA, vfA, t);

  #pragma unroll
  for (int qt = 0; qt < 2; ++qt) {
    float ls = l[qt] + __shfl_xor(l[qt], 32);
    float inv = 1.f / ls;
    u16* outp = AO + ((long)(b * Nn + q0w + qt * 32 + ln) * Cc) + h * HDd;
    #pragma unroll
    for (int dt = 0; dt < 2; ++dt) {
      #pragma unroll
      for (int qd = 0; qd < 4; ++qd) {  // reg quad -> d = dt*32 + 8*qd + 4*hi + 0..3
        uint2 st2 = {cvtpk2(o[qt][dt][4 * qd + 0] * inv, o[qt][dt][4 * qd + 1] * inv),
                     cvtpk2(o[qt][dt][4 * qd + 2] * inv, o[qt][dt][4 * qd + 3] * inv)};
        *(uint2*)(outp + dt * 32 + 8 * qd + 4 * hi) = st2;
      }
    }
  }
}

// ---------------- CLS-row scores (one block per (b,h), atomic accumulate) ----------------
__global__ __launch_bounds__(256) void k_cls(const u16* __restrict__ Q, const u16* __restrict__ K,
                                             const int* __restrict__ lens, float* __restrict__ scores) {
  int bh = blockIdx.x;  // 0..383
  int b = bh / Hh;
  int t = threadIdx.x;
  int len = lens[b];
  __shared__ float qrow[64];
  __shared__ float red[256];
  const u16* Qb = Q + (long)bh * Nn * HDd;
  const u16* Kb = K + (long)bh * Nn * HDd;
  if (t < 64) qrow[t] = bf2f(Qb[t]);   // CLS query, pre-scaled (log2 domain)
  __syncthreads();
  const bf16x8* kr0 = (const bf16x8*)(Kb + t * HDd);
  const bf16x8* kr1 = (const bf16x8*)(Kb + (t + 256) * HDd);
  float d0 = 0.f, d1 = 0.f;
  #pragma unroll
  for (int c8 = 0; c8 < 8; ++c8) {
    bf16x8 kv0 = kr0[c8], kv1 = kr1[c8];
    #pragma unroll
    for (int j = 0; j < 8; ++j) {
      float qv = qrow[c8 * 8 + j];
      d0 += qv * bf2f((u16)kv0[j]);
      d1 += qv * bf2f((u16)kv1[j]);
    }
  }
  float l0 = (t < len) ? d0 : -1e9f;
  float l1 = (t + 256 < len) ? d1 : -1e9f;
  red[t] = fmaxf(l0, l1);
  __syncthreads();
  for (int ss = 128; ss > 0; ss >>= 1) {
    if (t < ss) red[t] = fmaxf(red[t], red[t + ss]);
    __syncthreads();
  }
  float mx = red[0];
  __syncthreads();
  float e0 = fexp2(l0 - mx), e1 = fexp2(l1 - mx);
  red[t] = e0 + e1;
  __syncthreads();
  for (int ss = 128; ss > 0; ss >>= 1) {
    if (t < ss) red[t] += red[t + ss];
    __syncthreads();
  }
  float w = (1.f / 12.f) / red[0];
  if (t >= 1) atomicAdd(&scores[b * 511 + (t - 1)], e0 * w);
  atomicAdd(&scores[b * 511 + (t + 255)], e1 * w);
}

// ---------------- top-k (bitonic sort 512, desc score / asc idx) ----------------
__device__ __forceinline__ bool sless(float sa, int ia, float sb, int ib) {
  return (sa > sb) || (sa == sb && ia < ib);
}

__global__ __launch_bounds__(256) void k_topk(const float* __restrict__ scores,
                                              const int* __restrict__ lens, float* __restrict__ dout) {
  int b = blockIdx.x, t = threadIdx.x;
  __shared__ float sc[512];
  __shared__ int id[512];
  float ninf = -__builtin_inff();
  int len = lens[b];
  for (int i = t; i < 512; i += 256) {
    sc[i] = (i < 511 && (i + 1) < len) ? scores[b * 511 + i] : ninf;
    id[i] = i;
  }
  for (int k = 2; k <= 512; k <<= 1) {
    for (int j = k >> 1; j > 0; j >>= 1) {
      __syncthreads();
      for (int i = t; i < 512; i += 256) {
        int ixj = i ^ j;
        if (ixj > i) {
          float si = sc[i], sj = sc[ixj];
          int ii = id[i], ij = id[ixj];
          bool up = ((i & k) == 0);
          bool dosw = up ? sless(sj, ij, si, ii) : sless(si, ii, sj, ij);
          if (dosw) {
            sc[i] = sj; sc[ixj] = si;
            id[i] = ij; id[ixj] = ii;
          }
        }
      }
    }
  }
  __syncthreads();
  int left = (int)ceilf((float)(len - 1) * 0.7f);
  const long OFF_IDX = (long)Bb * Nn * Cc + (long)Bb * BND * Cc;
  for (int p = t; p < BND; p += 256) {
    dout[OFF_IDX + (long)b * BND + p] = (p < left) ? (float)id[p] : 1e9f;
  }
  if (b == 0 && t == 0) dout[OFF_IDX + (long)Bb * BND] = (float)BND;
}

__global__ __launch_bounds__(256) void k_bcast(float* __restrict__ dout) {
  long gid = (long)blockIdx.x * 256 + threadIdx.x;
  const long total = (long)Bb * BND * (Cc / 4);
  if (gid >= total) return;
  long bp = gid / (Cc / 4);
  int c4 = (int)(gid % (Cc / 4));
  const long OFF_INDEX = (long)Bb * Nn * Cc;
  const long OFF_IDX = OFF_INDEX + (long)Bb * BND * Cc;
  float v = dout[OFF_IDX + bp];
  float4 f = {v, v, v, v};
  *(float4*)&dout[OFF_INDEX + bp * Cc + (long)c4 * 4] = f;
}

// ---------------- launch ----------------
extern "C" void kernel_launch(void* const* d_in, const int* in_sizes, int n_in,
                              void* d_out, int out_size, void* d_ws, size_t ws_size,
                              hipStream_t stream) {
  const float* x = (const float*)d_in[0];
  const int* mask = (const int*)d_in[1];
  const float* wqkv = (const float*)d_in[2];
  const float* wproj = (const float*)d_in[3];
  const float* bproj = (const float*)d_in[4];
  float* out = (float*)d_out;

  char* ws = (char*)d_ws;
  u16* Qw  = (u16*)(ws);                    // 25165824 B
  u16* Kw  = (u16*)(ws + 25165824L);        // 25165824 B
  u16* Vtw = (u16*)(ws + 50331648L);        // 25165824 B (tiled layout)
  u16* XB  = (u16*)(ws + 75497472L);        // 25165824 B (x bf16; reused as attn out)
  u16* AO  = XB;
  u16* WQT = (u16*)(ws + 100663296L);       // 3538944 B
  u16* WPT = (u16*)(ws + 104202240L);       // 1179648 B
  float* SCO = (float*)(ws + 105381888L);   // 65536 B
  int* LEN = (int*)(ws + 105447424L);       // 128 B
  int* ORD = (int*)(ws + 105447552L);       // 128 B

  k_convx<<<12288, 256, 0, stream>>>(x, XB);
  k_transw<<<dim3(96, 24), 256, 0, stream>>>(wqkv, WQT, wproj, WPT);
  k_prep<<<1, 256, 0, stream>>>(mask, LEN, ORD, SCO);
  k_gemm2<0, 1><<<dim3(128, 12), 256, 0, stream>>>(XB, WQT, 0, Qw, Kw, nullptr, nullptr, nullptr);
  k_gemm2<0, 0><<<dim3(128, 6), 256, 0, stream>>>(XB, WQT, 1536, nullptr, nullptr, Vtw, nullptr, nullptr);
  k_attn<<<3072, 64, 0, stream>>>(Qw, Kw, Vtw, LEN, ORD, AO);
  k_gemm2<1, 1><<<dim3(128, 6), 256, 0, stream>>>(AO, WPT, 0, nullptr, nullptr, nullptr, out, bproj);
  k_cls<<<384, 256, 0, stream>>>(Qw, Kw, LEN, SCO);
  k_topk<<<32, 256, 0, stream>>>(SCO, LEN, out);
  k_bcast<<<8592, 256, 0, stream>>>(out);
}

// Round 20
// 218.164 us; speedup vs baseline: 1.9739x; 1.0076x over previous
//
#include <hip/hip_runtime.h>
#include <hip/hip_bf16.h>

#define Bb 32
#define Nn 512
#define Cc 768
#define Hh 12
#define HDd 64
#define BND 358
// Q is pre-scaled by SCALE*log2(e) in the QKV epilogue -> logits in log2 domain
#define QS 0.18033688f

typedef unsigned short u16;
typedef unsigned int u32;
typedef __attribute__((ext_vector_type(8))) short bf16x8;
typedef __attribute__((ext_vector_type(4))) float f32x4;
typedef __attribute__((ext_vector_type(16))) float f32x16;
typedef __attribute__((ext_vector_type(4))) int i32x4;

__device__ __forceinline__ f32x4 MFMA16(bf16x8 a, bf16x8 b, f32x4 c) {
  return __builtin_amdgcn_mfma_f32_16x16x32_bf16(a, b, c, 0, 0, 0);
}
__device__ __forceinline__ f32x16 MFMA32(bf16x8 a, bf16x8 b, f32x16 c) {
  return __builtin_amdgcn_mfma_f32_32x32x16_bf16(a, b, c, 0, 0, 0);
}

__device__ __forceinline__ float fexp2(float x) { return __builtin_amdgcn_exp2f(x); }  // raw v_exp_f32

__device__ __forceinline__ u32 f2bf(float f) {
  u32 u = __builtin_bit_cast(u32, f);
  return (u + 0x7fffu + ((u >> 16) & 1u)) >> 16;
}
__device__ __forceinline__ u32 packbf2(float a, float b) { return f2bf(a) | (f2bf(b) << 16); }
__device__ __forceinline__ u32 cvtpk2(float a, float b) {
  float2 f2 = {a, b};
  __hip_bfloat162 h = __float22bfloat162_rn(f2);   // v_cvt_pk_bf16_f32
  u32 r;
  __builtin_memcpy(&r, &h, 4);
  return r;
}
__device__ __forceinline__ float bf2f(u16 h) { return __builtin_bit_cast(float, (u32)h << 16); }

__device__ __forceinline__ void async_copy16(void* lds, const void* g) {
  __builtin_amdgcn_global_load_lds((const __attribute__((address_space(1))) void*)g,
                                   (__attribute__((address_space(3))) void*)lds, 16, 0, 0);
}

// ---------------- elementwise conversions ----------------

__global__ __launch_bounds__(256) void k_convx(const float* __restrict__ x, u16* __restrict__ xb) {
  int gid = blockIdx.x * 256 + threadIdx.x;
  if (gid >= (Bb * Nn * Cc) / 4) return;
  float4 v = *(const float4*)&x[gid * 4];
  u32 p0 = packbf2(v.x, v.y), p1 = packbf2(v.z, v.w);
  uint2 st = {p0, p1};
  *(uint2*)&xb[gid * 4] = st;
}

// fused weight transposes: blocks [0,72) -> wqkv (768x2304), [72,96) -> wproj (768x768)
__global__ __launch_bounds__(256) void k_transw(const float* __restrict__ wqkv, u16* __restrict__ wqt,
                                                const float* __restrict__ wproj, u16* __restrict__ wpt) {
  __shared__ float tbuf[32][33];
  int bx = blockIdx.x;
  const float* src;
  u16* dst;
  int Ccols, cx;
  if (bx < 72) { src = wqkv; dst = wqt; Ccols = 2304; cx = bx; }
  else         { src = wproj; dst = wpt; Ccols = 768; cx = bx - 72; }
  int c0 = cx * 32, r0 = blockIdx.y * 32;
  int lx = threadIdx.x & 31, ly = threadIdx.x >> 5;  // 32 x 8
  #pragma unroll
  for (int rr = ly; rr < 32; rr += 8) tbuf[rr][lx] = src[(long)(r0 + rr) * Ccols + c0 + lx];
  __syncthreads();
  #pragma unroll
  for (int cc = ly; cc < 32; cc += 8) dst[(long)(c0 + cc) * 768 + r0 + lx] = (u16)f2bf(tbuf[lx][cc]);
}

// fused prep: lens (key-mask row sums), len-interleaved batch order, SCO zeroing.
// Single block, 256 threads.
__global__ __launch_bounds__(256) void k_prep(const int* __restrict__ mask, int* __restrict__ lens,
                                              int* __restrict__ ord, float* __restrict__ sco) {
  __shared__ int part[256];
  __shared__ int ls[32];
  int t = threadIdx.x;
  int b = t >> 3, p = t & 7;                        // 8 threads per batch
  const int* mrow = mask + (long)b * Nn * Nn;
  int s = 0;
  #pragma unroll
  for (int i = 0; i < 64; ++i) s += mrow[i * 8 + p];  // coalesced across threads
  part[t] = s;
  __syncthreads();
  if (p == 0) {
    int tot = 0;
    #pragma unroll
    for (int j = 0; j < 8; ++j) tot += part[t + j];
    ls[b] = tot;
    lens[b] = tot;
  }
  __syncthreads();
  if (t < 32) {
    int mylen = ls[t];
    int rank = 0;
    #pragma unroll
    for (int j = 0; j < 32; ++j) {
      int lj = ls[j];
      rank += (lj > mylen || (lj == mylen && j < t)) ? 1 : 0;
    }
    int s2 = (rank < 16) ? (2 * rank) : (2 * (31 - rank) + 1);
    ord[s2] = t;
  }
  for (int i = t; i < Bb * 511; i += 256) sco[i] = 0.f;
}

// ---------------- merged QKV GEMM: 128x128 tile, BK=64, dbuf, 256 threads ----------------
// grid (128, 18). y<12: Q/K blocks (swapped MFMA; quad spans n -> 4 consecutive d
// -> uint2 store; Q pre-scaled). y>=12: V blocks (unswapped; quad spans m ->
// uint2 store into TILED V[(bh)][qi>>5][d][qi&31]).
__global__ __launch_bounds__(256) void k_gemmqkv(const u16* __restrict__ A, const u16* __restrict__ Bt,
                                                 u16* __restrict__ Qo, u16* __restrict__ Ko,
                                                 u16* __restrict__ Vto) {
  __shared__ u16 As[2][128 * 64];
  __shared__ u16 Bs[2][128 * 64];
  int m0 = blockIdx.x * 128;
  int nb = blockIdx.y * 128;
  bool sw = blockIdx.y < 12;   // block-uniform
  int t = threadIdx.x, lane = t & 63, wave = t >> 6;
  int wr = wave >> 1, wc = wave & 1;
  int qlane = lane & 15, g = lane >> 4;
  f32x4 acc[4][4] = {};

  auto stage = [&](int kt, int buf) {
    #pragma unroll
    for (int i = 0; i < 4; ++i) {
      int chunk = i * 256 + t;
      int row = chunk >> 3;
      int cp = (chunk & 7) << 4;
      int src = cp ^ ((row & 7) << 4);    // inverse-swizzled source byte-pos
      const u16* ga = A + (long)(m0 + row) * 768 + kt * 64 + (src >> 1);
      const u16* gb = Bt + (long)(nb + row) * 768 + kt * 64 + (src >> 1);
      async_copy16(&As[buf][(i * 256 + wave * 64) * 8], ga);
      async_copy16(&Bs[buf][(i * 256 + wave * 64) * 8], gb);
    }
  };

  auto compute = [&](int buf) {
    #pragma unroll
    for (int kk = 0; kk < 2; ++kk) {
      bf16x8 af[4], bf[4];
      #pragma unroll
      for (int x = 0; x < 4; ++x) {
        int ra = wr * 64 + x * 16 + qlane;
        int ca = (kk * 64 + g * 16) ^ ((ra & 7) << 4);   // swizzled read byte-pos
        af[x] = *(const bf16x8*)&As[buf][ra * 64 + (ca >> 1)];
        int rb = wc * 64 + x * 16 + qlane;
        int cb = (kk * 64 + g * 16) ^ ((rb & 7) << 4);
        bf[x] = *(const bf16x8*)&Bs[buf][rb * 64 + (cb >> 1)];
      }
      if (sw) {
        #pragma unroll
        for (int mi = 0; mi < 4; ++mi)
          #pragma unroll
          for (int ni = 0; ni < 4; ++ni) acc[mi][ni] = MFMA16(bf[ni], af[mi], acc[mi][ni]);
      } else {
        #pragma unroll
        for (int mi = 0; mi < 4; ++mi)
          #pragma unroll
          for (int ni = 0; ni < 4; ++ni) acc[mi][ni] = MFMA16(af[mi], bf[ni], acc[mi][ni]);
      }
    }
  };

  stage(0, 0);
  __syncthreads();
  int cur = 0;
  for (int kt = 0; kt < 12; ++kt) {
    if (kt < 11) stage(kt + 1, cur ^ 1);  // prefetch flies during compute
    compute(cur);
    __syncthreads();
    cur ^= 1;
  }

  if (sw) {
    #pragma unroll
    for (int mi = 0; mi < 4; ++mi) {
      int m = m0 + wr * 64 + mi * 16 + qlane;
      int b = m >> 9, qi = m & 511;
      #pragma unroll
      for (int ni = 0; ni < 4; ++ni) {
        int nf = nb + wc * 64 + ni * 16 + g * 4;
        int which = nf >= 768;
        int rem = nf - which * 768;
        int hh = rem >> 6, d0 = rem & 63;
        u16* dst = (which ? Ko : Qo) + ((long)(b * Hh + hh) * Nn + qi) * HDd + d0;
        float sc = which ? 1.f : QS;   // pre-scale Q into log2 softmax domain
        uint2 st = {packbf2(acc[mi][ni][0] * sc, acc[mi][ni][1] * sc),
                    packbf2(acc[mi][ni][2] * sc, acc[mi][ni][3] * sc)};
        *(uint2*)dst = st;
      }
    }
  } else {
    // V tiled: subtile = qi>>5 (4KB of 64d x 32k), within: d*32 + (qi&31)
    #pragma unroll
    for (int mi = 0; mi < 4; ++mi) {
      int m = m0 + wr * 64 + mi * 16 + g * 4;
      int b = m >> 9, qi = m & 511;
      #pragma unroll
      for (int ni = 0; ni < 4; ++ni) {
        int rem = nb + wc * 64 + ni * 16 + qlane - 1536;
        int hh = rem >> 6, d = rem & 63;
        u16* dst = Vto + (long)(b * Hh + hh) * (Nn * HDd) + (qi >> 5) * 2048 + d * 32 + (qi & 31);
        uint2 st = {packbf2(acc[mi][ni][0], acc[mi][ni][1]),
                    packbf2(acc[mi][ni][2], acc[mi][ni][3])};
        *(uint2*)dst = st;
      }
    }
  }
}

// ---------------- proj GEMM (R15 champion): 128x128 tile, BK=64, dbuf, 256 threads ----------------
__global__ __launch_bounds__(256) void k_gemmpr(const u16* __restrict__ A, const u16* __restrict__ Bt,
                                                float* __restrict__ Co, const float* __restrict__ bias) {
  __shared__ u16 As[2][128 * 64];
  __shared__ u16 Bs[2][128 * 64];
  int m0 = blockIdx.x * 128;
  int nb = blockIdx.y * 128;
  int t = threadIdx.x, lane = t & 63, wave = t >> 6;
  int wr = wave >> 1, wc = wave & 1;
  int qlane = lane & 15, g = lane >> 4;
  f32x4 acc[4][4] = {};

  auto stage = [&](int kt, int buf) {
    #pragma unroll
    for (int i = 0; i < 4; ++i) {
      int chunk = i * 256 + t;
      int row = chunk >> 3;
      int cp = (chunk & 7) << 4;
      int src = cp ^ ((row & 7) << 4);
      const u16* ga = A + (long)(m0 + row) * 768 + kt * 64 + (src >> 1);
      const u16* gb = Bt + (long)(nb + row) * 768 + kt * 64 + (src >> 1);
      async_copy16(&As[buf][(i * 256 + wave * 64) * 8], ga);
      async_copy16(&Bs[buf][(i * 256 + wave * 64) * 8], gb);
    }
  };

  auto compute = [&](int buf) {
    #pragma unroll
    for (int kk = 0; kk < 2; ++kk) {
      bf16x8 af[4], bf[4];
      #pragma unroll
      for (int x = 0; x < 4; ++x) {
        int ra = wr * 64 + x * 16 + qlane;
        int ca = (kk * 64 + g * 16) ^ ((ra & 7) << 4);
        af[x] = *(const bf16x8*)&As[buf][ra * 64 + (ca >> 1)];
        int rb = wc * 64 + x * 16 + qlane;
        int cb = (kk * 64 + g * 16) ^ ((rb & 7) << 4);
        bf[x] = *(const bf16x8*)&Bs[buf][rb * 64 + (cb >> 1)];
      }
      #pragma unroll
      for (int mi = 0; mi < 4; ++mi)
        #pragma unroll
        for (int ni = 0; ni < 4; ++ni)
          acc[mi][ni] = MFMA16(bf[ni], af[mi], acc[mi][ni]);   // swapped: quad spans n
    }
  };

  stage(0, 0);
  __syncthreads();
  int cur = 0;
  for (int kt = 0; kt < 12; ++kt) {
    if (kt < 11) stage(kt + 1, cur ^ 1);
    compute(cur);
    __syncthreads();
    cur ^= 1;
  }

  #pragma unroll
  for (int mi = 0; mi < 4; ++mi) {
    int m = m0 + wr * 64 + mi * 16 + qlane;
    #pragma unroll
    for (int ni = 0; ni < 4; ++ni) {
      int n0 = nb + wc * 64 + ni * 16 + g * 4;
      float4 bv = *(const float4*)&bias[n0];
      float4 st = {acc[mi][ni][0] + bv.x, acc[mi][ni][1] + bv.y,
                   acc[mi][ni][2] + bv.z, acc[mi][ni][3] + bv.w};
      *(float4*)&Co[(long)m * Cc + n0] = st;
    }
  }
}

// ---------------- fused attention v8 (R12/R15 champion): R10 grid + raw v_exp_f32 ----------------
// 3072 one-wave blocks. bid = chunk*384 + bh: all 8 q-chunks of one (b,h) share
// bid%8 -> same XCD L2; one batch's heads stream per XCD round (L2-friendly).
// b = ord[bh/12] (len-interleaved) balances per-CU work. 2-deep register
// prefetch (named buffers). exp2 = single v_exp_f32.
// NO min-waves bound (R18 lesson: capping VGPR below natural usage -> scratch spill).
__global__ __launch_bounds__(64) void k_attn(const u16* __restrict__ Q, const u16* __restrict__ K,
                                             const u16* __restrict__ Vt, const int* __restrict__ lens,
                                             const int* __restrict__ ord, u16* __restrict__ AO) {
  int lane = threadIdx.x;
  int bid = blockIdx.x;
  int bh = bid % (Bb * Hh);
  int chunk = bid / (Bb * Hh);
  int b = ord[bh / Hh];
  int h = bh % Hh;
  int q0w = chunk * 64;
  int ln = lane & 31, hi = lane >> 5;
  int len = lens[b];
  int nt = (len + 31) >> 5;

  const u16* Qb = Q + (long)(b * Hh + h) * Nn * HDd;
  const u16* Kb = K + (long)(b * Hh + h) * Nn * HDd;
  const u16* Vb = Vt + (long)(b * Hh + h) * Nn * HDd;  // tiled: 16 x (64d x 32k)

  // Q fragments: B-operand of mfma32 (Q^T): lane holds Q[q0+ln][ds*16+hi*8+j]
  bf16x8 qf[2][4];
  #pragma unroll
  for (int qt = 0; qt < 2; ++qt)
    #pragma unroll
    for (int ds = 0; ds < 4; ++ds)
      qf[qt][ds] = *(const bf16x8*)(Qb + (q0w + qt * 32 + ln) * HDd + ds * 16 + hi * 8);

  f32x16 o[2][2] = {};  // [qt][dt] : o^T[d][q], lane q=ln, 16 d-vals
  float l[2] = {0.f, 0.f};

  auto loadt = [&](bf16x8 (&kf)[4], bf16x8 (&vf)[2][2], int t) {
    int k0 = t * 32;
    #pragma unroll
    for (int ds = 0; ds < 4; ++ds)
      kf[ds] = *(const bf16x8*)(Kb + (k0 + ln) * HDd + ds * 16 + hi * 8);
    #pragma unroll
    for (int dt = 0; dt < 2; ++dt)
      #pragma unroll
      for (int ks = 0; ks < 2; ++ks)
        vf[dt][ks] = *(const bf16x8*)(Vb + t * 2048 + (dt * 32 + ln) * 32 + ks * 16 + hi * 8);
  };

  auto compute = [&](const bf16x8 (&kf)[4], const bf16x8 (&vf)[2][2], int t) {
    int k0 = t * 32;
    bool bdry = (k0 + 32 > len);
    int khi = k0 + 4 * hi;
    #pragma unroll
    for (int qt = 0; qt < 2; ++qt) {
      f32x16 st = {};
      #pragma unroll
      for (int ds = 0; ds < 4; ++ds) st = MFMA32(kf[ds], qf[qt][ds], st);
      // C-layout: row(key within 32) = (r&3)+8*(r>>2)+4*hi, col(q)=ln
      if (bdry) {
        #pragma unroll
        for (int r = 0; r < 16; ++r) {
          int key = khi + (r & 3) + 8 * (r >> 2);
          if (key >= len) st[r] = -1e9f;
        }
      }
      float p[16];
      #pragma unroll
      for (int r = 0; r < 16; ++r) p[r] = fexp2(st[r]);
      l[qt] += (((p[0] + p[1]) + (p[2] + p[3])) + ((p[4] + p[5]) + (p[6] + p[7]))) +
               (((p[8] + p[9]) + (p[10] + p[11])) + ((p[12] + p[13]) + (p[14] + p[15])));
      u32 wA0 = cvtpk2(p[0], p[1]), wA1 = cvtpk2(p[2], p[3]);
      u32 wA2 = cvtpk2(p[4], p[5]), wA3 = cvtpk2(p[6], p[7]);
      asm volatile("v_permlane32_swap_b32 %0, %1" : "+v"(wA0), "+v"(wA2));
      asm volatile("v_permlane32_swap_b32 %0, %1" : "+v"(wA1), "+v"(wA3));
      u32 wB0 = cvtpk2(p[8], p[9]), wB1 = cvtpk2(p[10], p[11]);
      u32 wB2 = cvtpk2(p[12], p[13]), wB3 = cvtpk2(p[14], p[15]);
      asm volatile("v_permlane32_swap_b32 %0, %1" : "+v"(wB0), "+v"(wB2));
      asm volatile("v_permlane32_swap_b32 %0, %1" : "+v"(wB1), "+v"(wB3));
      i32x4 bi0 = {(int)wA0, (int)wA1, (int)wA2, (int)wA3};
      i32x4 bi1 = {(int)wB0, (int)wB1, (int)wB2, (int)wB3};
      bf16x8 pb0 = __builtin_bit_cast(bf16x8, bi0);
      bf16x8 pb1 = __builtin_bit_cast(bf16x8, bi1);
      #pragma unroll
      for (int dt = 0; dt < 2; ++dt) {
        o[qt][dt] = MFMA32(vf[dt][0], pb0, o[qt][dt]);
        o[qt][dt] = MFMA32(vf[dt][1], pb1, o[qt][dt]);
      }
    }
  };

  // 2-deep software pipeline: named buffers (no runtime-indexed arrays)
  bf16x8 kfA[4], vfA[2][2], kfB[4], vfB[2][2];
  loadt(kfA, vfA, 0);
  int t = 0;
  #pragma unroll 1
  for (; t + 2 <= nt; t += 2) {
    loadt(kfB, vfB, t + 1);
    compute(kfA, vfA, t);
    if (t + 2 < nt) loadt(kfA, vfA, t + 2);
    compute(kfB, vfB, t + 1);
  }
  if (t < nt) compute(kfA, vfA, t);

  #pragma unroll
  for (int qt = 0; qt < 2; ++qt) {
    float ls = l[qt] + __shfl_xor(l[qt], 32);
    float inv = 1.f / ls;
    u16* outp = AO + ((long)(b * Nn + q0w + qt * 32 + ln) * Cc) + h * HDd;
    #pragma unroll
    for (int dt = 0; dt < 2; ++dt) {
      #pragma unroll
      for (int qd = 0; qd < 4; ++qd) {  // reg quad -> d = dt*32 + 8*qd + 4*hi + 0..3
        uint2 st2 = {cvtpk2(o[qt][dt][4 * qd + 0] * inv, o[qt][dt][4 * qd + 1] * inv),
                     cvtpk2(o[qt][dt][4 * qd + 2] * inv, o[qt][dt][4 * qd + 3] * inv)};
        *(uint2*)(outp + dt * 32 + 8 * qd + 4 * hi) = st2;
      }
    }
  }
}

// ---------------- CLS-row scores (one block per (b,h), atomic accumulate) ----------------
__global__ __launch_bounds__(256) void k_cls(const u16* __restrict__ Q, const u16* __restrict__ K,
                                             const int* __restrict__ lens, float* __restrict__ scores) {
  int bh = blockIdx.x;  // 0..383
  int b = bh / Hh;
  int t = threadIdx.x;
  int len = lens[b];
  __shared__ float qrow[64];
  __shared__ float red[256];
  const u16* Qb = Q + (long)bh * Nn * HDd;
  const u16* Kb = K + (long)bh * Nn * HDd;
  if (t < 64) qrow[t] = bf2f(Qb[t]);   // CLS query, pre-scaled (log2 domain)
  __syncthreads();
  const bf16x8* kr0 = (const bf16x8*)(Kb + t * HDd);
  const bf16x8* kr1 = (const bf16x8*)(Kb + (t + 256) * HDd);
  float d0 = 0.f, d1 = 0.f;
  #pragma unroll
  for (int c8 = 0; c8 < 8; ++c8) {
    bf16x8 kv0 = kr0[c8], kv1 = kr1[c8];
    #pragma unroll
    for (int j = 0; j < 8; ++j) {
      float qv = qrow[c8 * 8 + j];
      d0 += qv * bf2f((u16)kv0[j]);
      d1 += qv * bf2f((u16)kv1[j]);
    }
  }
  float l0 = (t < len) ? d0 : -1e9f;
  float l1 = (t + 256 < len) ? d1 : -1e9f;
  red[t] = fmaxf(l0, l1);
  __syncthreads();
  for (int ss = 128; ss > 0; ss >>= 1) {
    if (t < ss) red[t] = fmaxf(red[t], red[t + ss]);
    __syncthreads();
  }
  float mx = red[0];
  __syncthreads();
  float e0 = fexp2(l0 - mx), e1 = fexp2(l1 - mx);
  red[t] = e0 + e1;
  __syncthreads();
  for (int ss = 128; ss > 0; ss >>= 1) {
    if (t < ss) red[t] += red[t + ss];
    __syncthreads();
  }
  float w = (1.f / 12.f) / red[0];
  if (t >= 1) atomicAdd(&scores[b * 511 + (t - 1)], e0 * w);
  atomicAdd(&scores[b * 511 + (t + 255)], e1 * w);
}

// ---------------- top-k (bitonic sort 512, desc score / asc idx) ----------------
__device__ __forceinline__ bool sless(float sa, int ia, float sb, int ib) {
  return (sa > sb) || (sa == sb && ia < ib);
}

__global__ __launch_bounds__(256) void k_topk(const float* __restrict__ scores,
                                              const int* __restrict__ lens, float* __restrict__ dout) {
  int b = blockIdx.x, t = threadIdx.x;
  __shared__ float sc[512];
  __shared__ int id[512];
  float ninf = -__builtin_inff();
  int len = lens[b];
  for (int i = t; i < 512; i += 256) {
    sc[i] = (i < 511 && (i + 1) < len) ? scores[b * 511 + i] : ninf;
    id[i] = i;
  }
  for (int k = 2; k <= 512; k <<= 1) {
    for (int j = k >> 1; j > 0; j >>= 1) {
      __syncthreads();
      for (int i = t; i < 512; i += 256) {
        int ixj = i ^ j;
        if (ixj > i) {
          float si = sc[i], sj = sc[ixj];
          int ii = id[i], ij = id[ixj];
          bool up = ((i & k) == 0);
          bool dosw = up ? sless(sj, ij, si, ii) : sless(si, ii, sj, ij);
          if (dosw) {
            sc[i] = sj; sc[ixj] = si;
            id[i] = ij; id[ixj] = ii;
          }
        }
      }
    }
  }
  __syncthreads();
  int left = (int)ceilf((float)(len - 1) * 0.7f);
  const long OFF_IDX = (long)Bb * Nn * Cc + (long)Bb * BND * Cc;
  for (int p = t; p < BND; p += 256) {
    dout[OFF_IDX + (long)b * BND + p] = (p < left) ? (float)id[p] : 1e9f;
  }
  if (b == 0 && t == 0) dout[OFF_IDX + (long)Bb * BND] = (float)BND;
}

__global__ __launch_bounds__(256) void k_bcast(float* __restrict__ dout) {
  long gid = (long)blockIdx.x * 256 + threadIdx.x;
  const long total = (long)Bb * BND * (Cc / 4);
  if (gid >= total) return;
  long bp = gid / (Cc / 4);
  int c4 = (int)(gid % (Cc / 4));
  const long OFF_INDEX = (long)Bb * Nn * Cc;
  const long OFF_IDX = OFF_INDEX + (long)Bb * BND * Cc;
  float v = dout[OFF_IDX + bp];
  float4 f = {v, v, v, v};
  *(float4*)&dout[OFF_INDEX + bp * Cc + (long)c4 * 4] = f;
}

// ---------------- launch ----------------
extern "C" void kernel_launch(void* const* d_in, const int* in_sizes, int n_in,
                              void* d_out, int out_size, void* d_ws, size_t ws_size,
                              hipStream_t stream) {
  const float* x = (const float*)d_in[0];
  const int* mask = (const int*)d_in[1];
  const float* wqkv = (const float*)d_in[2];
  const float* wproj = (const float*)d_in[3];
  const float* bproj = (const float*)d_in[4];
  float* out = (float*)d_out;

  char* ws = (char*)d_ws;
  u16* Qw  = (u16*)(ws);                    // 25165824 B
  u16* Kw  = (u16*)(ws + 25165824L);        // 25165824 B
  u16* Vtw = (u16*)(ws + 50331648L);        // 25165824 B (tiled layout)
  u16* XB  = (u16*)(ws + 75497472L);        // 25165824 B (x bf16; reused as attn out)
  u16* AO  = XB;
  u16* WQT = (u16*)(ws + 100663296L);       // 3538944 B
  u16* WPT = (u16*)(ws + 104202240L);       // 1179648 B
  float* SCO = (float*)(ws + 105381888L);   // 65536 B
  int* LEN = (int*)(ws + 105447424L);       // 128 B
  int* ORD = (int*)(ws + 105447552L);       // 128 B

  k_convx<<<12288, 256, 0, stream>>>(x, XB);
  k_transw<<<dim3(96, 24), 256, 0, stream>>>(wqkv, WQT, wproj, WPT);
  k_prep<<<1, 256, 0, stream>>>(mask, LEN, ORD, SCO);
  k_gemmqkv<<<dim3(128, 18), 256, 0, stream>>>(XB, WQT, Qw, Kw, Vtw);
  k_attn<<<3072, 64, 0, stream>>>(Qw, Kw, Vtw, LEN, ORD, AO);
  k_gemmpr<<<dim3(128, 6), 256, 0, stream>>>(AO, WPT, out, bproj);
  k_cls<<<384, 256, 0, stream>>>(Qw, Kw, LEN, SCO);
  k_topk<<<32, 256, 0, stream>>>(SCO, LEN, out);
  k_bcast<<<8592, 256, 0, stream>>>(out);
}